// Round 6
// baseline (173.848 us; speedup 1.0000x reference)
//
#include <hip/hip_runtime.h>
#include <hip/hip_fp16.h>

#define NP    128   // planets per batch
#define NH    64    // hidden dim
#define LDH   72    // slab row stride in f16 elems (16B-aligned rows)
#define ITERS 4     // batches per wave

typedef __attribute__((ext_vector_type(8))) _Float16 f16x8;   // MFMA A/B operand, K=32
typedef __attribute__((ext_vector_type(4))) _Float16 f16x4;   // MFMA A/B operand, K=16
typedef __attribute__((ext_vector_type(2))) __fp16  hf16x2;   // return type of cvt_pkrtz
typedef __attribute__((ext_vector_type(4))) float f32x4;

union FragK32 { f16x8 v; unsigned int u[4]; };
union FragK16 { f16x4 v; unsigned int u[2]; };

__device__ __forceinline__ unsigned int pack_pkrtz(float a, float b) {
    hf16x2 t = __builtin_amdgcn_cvt_pkrtz(a, b);
    return __builtin_bit_cast(unsigned int, t);
}

// One wave (64 threads) per block; each wave owns ITERS consecutive batches.
// No __syncthreads anywhere: all LDS traffic is within-wave, ordered by
// explicit s_waitcnt lgkmcnt(0).
__global__ void __launch_bounds__(64, 3) gnn_wave(
    const float* __restrict__ planet_xy,  // [B][P][2]
    const float* __restrict__ planet_m,   // [P]
    const float* __restrict__ ast_xy,     // [B][2]
    const float* __restrict__ W1,         // [4][64]
    const float* __restrict__ b1,         // [64]
    const float* __restrict__ W2,         // [64][64]
    const float* __restrict__ b2,         // [64]
    float* __restrict__ out)              // [B][64]
{
    __shared__ alignas(16) unsigned short slab[2][16 * LDH];  // h slab double-buffer

    const int lane = threadIdx.x;
    const int q    = lane >> 4;
    const int lm   = lane & 15;
    const bool q0  = (q == 0);

    // ---- build weight fragments in-registers (W1/W2 are L2-hot) ----
    // layer1 (transposed, 16x16x16): A[m=h][k=feat], lane holds k=4q+j.
    FragK16 w1f[4];
    #pragma unroll
    for (int mt = 0; mt < 4; mt++) {
        float a0 = W1[0 * NH + 16 * mt + lm];
        float a1 = W1[1 * NH + 16 * mt + lm];
        float a2 = W1[2 * NH + 16 * mt + lm];
        float a3 = W1[3 * NH + 16 * mt + lm];
        w1f[mt].u[0] = q0 ? pack_pkrtz(a0, a1) : 0u;
        w1f[mt].u[1] = q0 ? pack_pkrtz(a2, a3) : 0u;
    }
    // layer2 (16x16x32): B[k=32kk+8q+j][n=16np+lm] = W2[k][n]
    FragK32 w2f[2][4];
    #pragma unroll
    for (int kk = 0; kk < 2; kk++)
        #pragma unroll
        for (int np = 0; np < 4; np++)
            #pragma unroll
            for (int jp = 0; jp < 4; jp++) {
                float r0 = W2[(32 * kk + 8 * q + 2 * jp + 0) * NH + 16 * np + lm];
                float r1 = W2[(32 * kk + 8 * q + 2 * jp + 1) * NH + 16 * np + lm];
                w2f[kk][np].u[jp] = pack_pkrtz(r0, r1);
            }

    // bias fragments: b1 as layer1 C-init (rows 16mt+4q..+3); b2 as layer2 C-init
    f32x4 b1f[4];
    #pragma unroll
    for (int mt = 0; mt < 4; mt++)
        b1f[mt] = *(const f32x4*)&b1[16 * mt + 4 * q];
    f32x4 b2f[4];
    #pragma unroll
    for (int np = 0; np < 4; np++) {
        float v = b2[16 * np + lm];
        b2f[np] = (f32x4){v, v, v, v};
    }

    // batch-invariant planet masses: planet 16*i + lm
    float pmv[8];
    #pragma unroll
    for (int i = 0; i < 8; i++)
        pmv[i] = planet_m[16 * i + lm];

    int b = blockIdx.x * ITERS;

    for (int it = 0; it < ITERS; ++it, ++b) {
        const float2 axy = *(const float2*)&ast_xy[2 * b];
        // all 16 planet pairs this wave needs (lane lm's planets: 16*i+lm)
        float2 pxy[8];
        #pragma unroll
        for (int i = 0; i < 8; i++)
            pxy[i] = *(const float2*)&planet_xy[((size_t)b * NP + 16 * i + lm) * 2];

        float sums[4] = {0.f, 0.f, 0.f, 0.f};

        // ---- produce slab 0 (layer1 for planets 0..15) ----
        {
            float dx = pxy[0].x - axy.x, dy = pxy[0].y - axy.y;
            float inv = __builtin_amdgcn_rsqf(fmaf(dx, dx, fmaf(dy, dy, 1e-6f)));
            FragK16 bf;
            bf.u[0] = q0 ? pack_pkrtz(dx, dy) : 0u;
            bf.u[1] = q0 ? pack_pkrtz(inv, pmv[0]) : 0u;
            #pragma unroll
            for (int mt = 0; mt < 4; mt++) {
                f32x4 c = __builtin_amdgcn_mfma_f32_16x16x16f16(w1f[mt].v, bf.v, b1f[mt], 0, 0, 0);
                unsigned int d0 = pack_pkrtz(fmaxf(c[0], 0.f), fmaxf(c[1], 0.f));
                unsigned int d1 = pack_pkrtz(fmaxf(c[2], 0.f), fmaxf(c[3], 0.f));
                *(uint2*)&slab[0][lm * LDH + 4 * q + 16 * mt] = make_uint2(d0, d1);
            }
        }

        #pragma unroll
        for (int mi = 0; mi < 8; ++mi) {
            const int buf = mi & 1;
            // ensure this slab's ds_writes have completed (within-wave ordering)
            asm volatile("s_waitcnt lgkmcnt(0)" ::: "memory");
            // layer2 A-fragments for planets 16mi..16mi+15 (lane: row lm, k=32kk+8q+j)
            f16x8 a0 = *(const f16x8*)&slab[buf][lm * LDH + 0  + 8 * q];
            f16x8 a1 = *(const f16x8*)&slab[buf][lm * LDH + 32 + 8 * q];

            // produce next slab while the reads are in flight
            if (mi < 7) {
                float dx = pxy[mi + 1].x - axy.x, dy = pxy[mi + 1].y - axy.y;
                float inv = __builtin_amdgcn_rsqf(fmaf(dx, dx, fmaf(dy, dy, 1e-6f)));
                FragK16 bf;
                bf.u[0] = q0 ? pack_pkrtz(dx, dy) : 0u;
                bf.u[1] = q0 ? pack_pkrtz(inv, pmv[mi + 1]) : 0u;
                #pragma unroll
                for (int mt = 0; mt < 4; mt++) {
                    f32x4 c = __builtin_amdgcn_mfma_f32_16x16x16f16(w1f[mt].v, bf.v, b1f[mt], 0, 0, 0);
                    unsigned int d0 = pack_pkrtz(fmaxf(c[0], 0.f), fmaxf(c[1], 0.f));
                    unsigned int d1 = pack_pkrtz(fmaxf(c[2], 0.f), fmaxf(c[3], 0.f));
                    *(uint2*)&slab[buf ^ 1][lm * LDH + 4 * q + 16 * mt] = make_uint2(d0, d1);
                }
            }

            // layer2: msg tile (16 planets x 64 cols), bias via C-operand
            #pragma unroll
            for (int np = 0; np < 4; np++) {
                f32x4 acc = __builtin_amdgcn_mfma_f32_16x16x32_f16(a0, w2f[0][np].v, b2f[np], 0, 0, 0);
                acc = __builtin_amdgcn_mfma_f32_16x16x32_f16(a1, w2f[1][np].v, acc, 0, 0, 0);
                sums[np] += fmaxf(acc[0], 0.f);
                sums[np] += fmaxf(acc[1], 0.f);
                sums[np] += fmaxf(acc[2], 0.f);
                sums[np] += fmaxf(acc[3], 0.f);
            }
        }

        // ---- cross-quad reduction + store (cols 16np+lm live in all quads) ----
        #pragma unroll
        for (int np = 0; np < 4; np++) {
            float s = sums[np];
            s += __shfl_xor(s, 16, 64);
            s += __shfl_xor(s, 32, 64);
            if (q0) out[(size_t)b * NH + 16 * np + lm] = s;
        }
    }
}

extern "C" void kernel_launch(void* const* d_in, const int* in_sizes, int n_in,
                              void* d_out, int out_size, void* d_ws, size_t ws_size,
                              hipStream_t stream) {
    const float* planet_xy = (const float*)d_in[0];
    const float* planet_m  = (const float*)d_in[1];
    const float* ast_xy    = (const float*)d_in[2];
    const float* W1        = (const float*)d_in[3];
    const float* b1        = (const float*)d_in[4];
    const float* W2        = (const float*)d_in[5];
    const float* b2        = (const float*)d_in[6];
    float* outp            = (float*)d_out;

    const int B = in_sizes[2] / 2;   // ast_xy is [B][2]
    const int grid = (B + ITERS - 1) / ITERS;

    gnn_wave<<<grid, 64, 0, stream>>>(planet_xy, planet_m, ast_xy, W1, b1, W2, b2, outp);
}